// Round 8
// baseline (266.141 us; speedup 1.0000x reference)
//
#include <hip/hip_runtime.h>
#include <hip/hip_bf16.h>

constexpr int Bc = 16, Dc = 64, Tc = 4096, Ec = 1024;
constexpr int NROW = Bc * Tc;          // 65536 rows of dim 64
constexpr float DECAYF = 0.99f;
constexpr float OMDF   = 0.01f;
constexpr float EPSF   = 1e-5f;

typedef short bf16x8 __attribute__((ext_vector_type(8)));
typedef float f32x4  __attribute__((ext_vector_type(4)));

// ---- d_out layout (floats, ref return order) ----
constexpr size_t O_EI  = 0;         // embed_idx [B,T,D]   4194304
constexpr size_t O_QX  = 4194304;   // qx [B,D,T]          4194304
constexpr size_t O_IDX = 8388608;   // quantized_idx [B,T]   65536
constexpr size_t O_EMB = 8454144;   // new_embedding [E,D]   65536
constexpr size_t O_ESZ = 8519680;   // new_ema_size [E]       1024
constexpr size_t O_EMW = 8520704;   // new_ema_w [D,E]       65536

// ---- scratch inside d_out's [0, 8388608) floats. Produced by decomp,
// consumed by gemm/esum, only THEN overwritten by the epilogue. ----
constexpr size_t S_XH = 0;          // ushort plane 65536x64 = 2097152 floats
constexpr size_t S_XM = 2097152;
constexpr size_t S_XL = 4194304;
constexpr size_t S_EH = 6291456;    // ushort plane 1024x64 = 32768 floats
constexpr size_t S_EM = 6324224;
constexpr size_t S_EL = 6356992;
constexpr size_t S_E2 = 6389760;    // 1024 floats
constexpr size_t S_X2 = 6424576;    // 65536 floats (ends 6490112)
constexpr size_t S_P  = 6557696;    // esum partials [16][64][1024] = 1048576
                                    // floats (ends 7606272 < 8388608)

// ---- ws layout (floats): counts[0..1024) | esum[1024..66560) | norm[66560..67584)

__device__ inline unsigned short bf16bits(float v) {
  union { __hip_bfloat16 b; unsigned short u; } c;
  c.b = __float2bfloat16(v);           // RNE
  return c.u;
}
__device__ inline float bf16val(unsigned short u) {
  union { unsigned u32; float f; } c;
  c.u32 = ((unsigned)u) << 16;         // bf16 -> f32 is exact bit expansion
  return c.f;
}
// exact 3-term split: x = h + m + l + eps, |eps| <= 2^-27 |x|
__device__ inline void split3(float x, unsigned short& h, unsigned short& m,
                              unsigned short& l) {
  h = bf16bits(x);
  float r1 = x - bf16val(h);           // exact (Sterbenz)
  m = bf16bits(r1);
  float r2 = r1 - bf16val(m);          // exact
  l = bf16bits(r2);
}

__device__ inline void pack8(unsigned short* s, uint4* dst) {
  uint4 v;
  v.x = (unsigned)s[0] | ((unsigned)s[1] << 16);
  v.y = (unsigned)s[2] | ((unsigned)s[3] << 16);
  v.z = (unsigned)s[4] | ((unsigned)s[5] << 16);
  v.w = (unsigned)s[6] | ((unsigned)s[7] << 16);
  *dst = v;
}

// ---- decomp_x: lane=row; coalesced x read; x2 (exact np-pairwise); 3 planes ----
__global__ __launch_bounds__(256) void decomp_x(const float* __restrict__ x,
                                                float* __restrict__ out) {
  const int row = blockIdx.x * 256 + threadIdx.x;
  const int b = row >> 12, t = row & (Tc - 1);
  const float* xrow = x + (size_t)b * Dc * Tc + t;
  float xv[64];
  #pragma unroll
  for (int d = 0; d < Dc; ++d) xv[d] = xrow[(size_t)d * Tc];

  float x2;
  {
    #pragma clang fp contract(off)
    float r[8];
    #pragma unroll
    for (int j = 0; j < 8; ++j) r[j] = xv[j] * xv[j];
    #pragma unroll
    for (int k = 1; k < 8; ++k) {
      #pragma unroll
      for (int j = 0; j < 8; ++j) r[j] += xv[8 * k + j] * xv[8 * k + j];
    }
    x2 = ((r[0] + r[1]) + (r[2] + r[3])) + ((r[4] + r[5]) + (r[6] + r[7]));
  }
  out[S_X2 + row] = x2;

  uint4* ph = (uint4*)((unsigned short*)(out + S_XH) + (size_t)row * 64);
  uint4* pm = (uint4*)((unsigned short*)(out + S_XM) + (size_t)row * 64);
  uint4* pl = (uint4*)((unsigned short*)(out + S_XL) + (size_t)row * 64);
  #pragma unroll
  for (int k = 0; k < 8; ++k) {
    unsigned short hs[8], ms[8], ls[8];
    #pragma unroll
    for (int j = 0; j < 8; ++j) split3(xv[8 * k + j], hs[j], ms[j], ls[j]);
    pack8(hs, ph + k); pack8(ms, pm + k); pack8(ls, pl + k);
  }
}

// ---- decomp_e: thread=codeword; e2 (exact np-pairwise); 3 planes ----
__global__ __launch_bounds__(256) void decomp_e(const float* __restrict__ emb,
                                                float* __restrict__ out) {
  const int c = blockIdx.x * 256 + threadIdx.x;
  if (c >= Ec) return;
  const float* ep = emb + (size_t)c * Dc;
  float ev[64];
  #pragma unroll
  for (int d = 0; d < Dc; ++d) ev[d] = ep[d];

  float e2;
  {
    #pragma clang fp contract(off)
    float r[8];
    #pragma unroll
    for (int j = 0; j < 8; ++j) r[j] = ev[j] * ev[j];
    #pragma unroll
    for (int k = 1; k < 8; ++k) {
      #pragma unroll
      for (int j = 0; j < 8; ++j) r[j] += ev[8 * k + j] * ev[8 * k + j];
    }
    e2 = ((r[0] + r[1]) + (r[2] + r[3])) + ((r[4] + r[5]) + (r[6] + r[7]));
  }
  out[S_E2 + c] = e2;

  uint4* ph = (uint4*)((unsigned short*)(out + S_EH) + (size_t)c * 64);
  uint4* pm = (uint4*)((unsigned short*)(out + S_EM) + (size_t)c * 64);
  uint4* pl = (uint4*)((unsigned short*)(out + S_EL) + (size_t)c * 64);
  #pragma unroll
  for (int k = 0; k < 8; ++k) {
    unsigned short hs[8], ms[8], ls[8];
    #pragma unroll
    for (int j = 0; j < 8; ++j) split3(ev[8 * k + j], hs[j], ms[j], ls[j]);
    pack8(hs, ph + k); pack8(ms, pm + k); pack8(ls, pl + k);
  }
}

// ---- gemm_argmin: wave = 32 rows (2 M-tiles), scans all 1024 cw in 16-wide
// N-tiles. 6-product bf16 MFMA chain = fp32 dot to ~1e-9.
// R7 lesson: launch_bounds(256,2) is a MINIMUM waves/EU; allocator targeted
// ~6 waves/EU -> 76 VGPRs -> A-frags rematerialized from memory every nt ->
// latency-chain-bound at 20% MfmaUtil. amdgpu_waves_per_eu(2,2) pins the
// budget to the grid-limited occupancy (2 waves/SIMD -> 256 VGPR cap). ----
__global__ __launch_bounds__(256)
__attribute__((amdgpu_waves_per_eu(2, 2)))
void gemm_argmin(float* __restrict__ out) {
  const int lane = threadIdx.x & 63;
  const int wave = threadIdx.x >> 6;
  const int col  = lane & 15;         // MFMA n / C-col
  const int quad = lane >> 4;
  const int rowbase = blockIdx.x * 128 + wave * 32;

  const unsigned short* XH = (const unsigned short*)(out + S_XH);
  const unsigned short* XM = (const unsigned short*)(out + S_XM);
  const unsigned short* XL = (const unsigned short*)(out + S_XL);
  const unsigned short* EH = (const unsigned short*)(out + S_EH);
  const unsigned short* EM = (const unsigned short*)(out + S_EM);
  const unsigned short* EL = (const unsigned short*)(out + S_EL);
  const float* E2 = out + S_E2;
  const float* X2 = out + S_X2;

  bf16x8 a[12];
  #pragma unroll
  for (int mt = 0; mt < 2; ++mt) {
    size_t ao = (size_t)(rowbase + mt * 16 + col) * 64 + quad * 8;
    a[mt * 6 + 0] = *(const bf16x8*)(XH + ao);
    a[mt * 6 + 1] = *(const bf16x8*)(XH + ao + 32);
    a[mt * 6 + 2] = *(const bf16x8*)(XM + ao);
    a[mt * 6 + 3] = *(const bf16x8*)(XM + ao + 32);
    a[mt * 6 + 4] = *(const bf16x8*)(XL + ao);
    a[mt * 6 + 5] = *(const bf16x8*)(XL + ao + 32);
  }
  float x2v[8];
  #pragma unroll
  for (int mt = 0; mt < 2; ++mt)
    #pragma unroll
    for (int r = 0; r < 4; ++r)
      x2v[mt * 4 + r] = X2[rowbase + mt * 16 + quad * 4 + r];

  float best[8];
  int bidx[8];
  #pragma unroll
  for (int i = 0; i < 8; ++i) { best[i] = 3.4e38f; bidx[i] = 0; }

  bf16x8 b0[6], b1[6];
  float e20, e21;

  auto loadB = [&](int nt, bf16x8 (&bb)[6], float& e2v) {
    size_t bo = (size_t)(nt * 16 + col) * 64 + quad * 8;
    bb[0] = *(const bf16x8*)(EH + bo);
    bb[1] = *(const bf16x8*)(EH + bo + 32);
    bb[2] = *(const bf16x8*)(EM + bo);
    bb[3] = *(const bf16x8*)(EM + bo + 32);
    bb[4] = *(const bf16x8*)(EL + bo);
    bb[5] = *(const bf16x8*)(EL + bo + 32);
    e2v = E2[nt * 16 + col];
  };

  auto score = [&](int nt, const bf16x8 (&bb)[6], float e2v) {
    f32x4 acc0 = {0.f, 0.f, 0.f, 0.f};
    f32x4 acc1 = {0.f, 0.f, 0.f, 0.f};
    const int PA[6] = {0, 0, 1, 1, 0, 2};   // products hh,hm,mh,mm,hl,lh
    const int PB[6] = {0, 1, 0, 1, 2, 0};
    #pragma unroll
    for (int p = 0; p < 6; ++p) {
      #pragma unroll
      for (int s = 0; s < 2; ++s) {
        bf16x8 bf = bb[PB[p] * 2 + s];
        acc0 = __builtin_amdgcn_mfma_f32_16x16x32_bf16(a[PA[p] * 2 + s], bf, acc0, 0, 0, 0);
        acc1 = __builtin_amdgcn_mfma_f32_16x16x32_bf16(a[6 + PA[p] * 2 + s], bf, acc1, 0, 0, 0);
      }
    }
    const int cwv = nt * 16 + col;
    #pragma unroll
    for (int r = 0; r < 4; ++r) {
      {
        float q = __builtin_fmaf(-2.0f, acc0[r], e2v);  // fl(e2 - 2*dot)
        q = q + x2v[r];                                  // fl(+ x2)
        if (q < best[r]) { best[r] = q; bidx[r] = cwv; }
      }
      {
        float q = __builtin_fmaf(-2.0f, acc1[r], e2v);
        q = q + x2v[4 + r];
        if (q < best[4 + r]) { best[4 + r] = q; bidx[4 + r] = cwv; }
      }
    }
  };

  loadB(0, b0, e20);
  for (int nt = 0; nt < 64; nt += 2) {
    loadB(nt + 1, b1, e21);
    score(nt, b0, e20);
    if (nt + 2 < 64) loadB(nt + 2, b0, e20);
    score(nt + 1, b1, e21);
  }

  // cross-lane argmin within each 16-lane col group (ties -> lowest cw index)
  #pragma unroll
  for (int i = 0; i < 8; ++i) {
    float bq = best[i];
    int bi = bidx[i];
    #pragma unroll
    for (int m = 1; m <= 8; m <<= 1) {
      float qo = __shfl_xor(bq, m, 64);
      int io = __shfl_xor(bi, m, 64);
      bool take = (qo < bq) || (qo == bq && io < bi);
      bq = take ? qo : bq;
      bi = take ? io : bi;
    }
    if (col == 0) {
      int mt = i >> 2, r = i & 3;
      int row = rowbase + mt * 16 + quad * 4 + r;
      out[O_IDX + row] = (float)bi;   // C row = quad*4+reg [m89]
    }
  }
}

// ---- esum_partial: segmented reduction of x into embed_sum via LDS.
// grid (16 chunks, 8 d-slices), block 256. Reads XH/XM/XL planes (x to 2^-27)
// + idx; LDS float atomics; plain-store partials to S_P. ----
__global__ __launch_bounds__(256) void esum_partial(float* __restrict__ out,
                                                    float* __restrict__ ws) {
  const int c = blockIdx.x;       // row chunk, 4096 rows
  const int s = blockIdx.y;       // d-slice of 8
  __shared__ float acc[8 * 1024];
  __shared__ float cnt[1024];
  for (int i = threadIdx.x; i < 8192; i += 256) acc[i] = 0.f;
  if (s == 0)
    for (int i = threadIdx.x; i < 1024; i += 256) cnt[i] = 0.f;
  __syncthreads();

  const unsigned short* XH = (const unsigned short*)(out + S_XH);
  const unsigned short* XM = (const unsigned short*)(out + S_XM);
  const unsigned short* XL = (const unsigned short*)(out + S_XL);

  for (int it = 0; it < 16; ++it) {
    const int r = c * 4096 + it * 256 + threadIdx.x;
    const int bi = (int)out[O_IDX + r];
    const size_t off = (size_t)r * 64 + s * 8;
    const uint4 h = *(const uint4*)(XH + off);
    const uint4 m = *(const uint4*)(XM + off);
    const uint4 l = *(const uint4*)(XL + off);

#define DOPAIR(k, HW, MW, LW)                                                  \
    {                                                                          \
      float v0 = (bf16val((unsigned short)(HW)) +                              \
                  bf16val((unsigned short)(MW))) +                             \
                 bf16val((unsigned short)(LW));                                \
      float v1 = (bf16val((unsigned short)((HW) >> 16)) +                      \
                  bf16val((unsigned short)((MW) >> 16))) +                     \
                 bf16val((unsigned short)((LW) >> 16));                        \
      atomicAdd(&acc[(2 * (k) + 0) * 1024 + bi], v0);                          \
      atomicAdd(&acc[(2 * (k) + 1) * 1024 + bi], v1);                          \
    }
    DOPAIR(0, h.x, m.x, l.x)
    DOPAIR(1, h.y, m.y, l.y)
    DOPAIR(2, h.z, m.z, l.z)
    DOPAIR(3, h.w, m.w, l.w)
#undef DOPAIR
    if (s == 0) atomicAdd(&cnt[bi], 1.0f);
  }
  __syncthreads();

  float* part = out + S_P + ((size_t)c * 64 + s * 8) * 1024;
  for (int i = threadIdx.x; i < 8192; i += 256) part[i] = acc[i];
  if (s == 0)
    for (int i = threadIdx.x; i < 1024; i += 256)
      atomicAdd(&ws[i], cnt[i]);    // 16 chunks x 1024 = 16k global atomics
}

// ---- esum_reduce: esum[i] = sum over 16 chunk partials ----
__global__ __launch_bounds__(256) void esum_reduce(const float* __restrict__ out,
                                                   float* __restrict__ ws) {
  const int i = blockIdx.x * 256 + threadIdx.x;  // 0..65535 (= d*1024+e)
  float v = 0.f;
  #pragma unroll
  for (int c = 0; c < 16; ++c) v += out[S_P + (size_t)c * 65536 + i];
  ws[1024 + i] = v;
}

// ---- epilogue: pure streaming: read x/idx, gather emb, write embed_idx+qx ----
__global__ __launch_bounds__(256) void epilogue_kernel(
    const float* __restrict__ x, const float* __restrict__ emb,
    float* __restrict__ out) {
  const int row = blockIdx.x * 256 + threadIdx.x;
  const int b = row >> 12, t = row & (Tc - 1);
  const float* xrow = x + (size_t)b * Dc * Tc + t;

  const int bi = (int)out[O_IDX + row];

  const float4* eb = (const float4*)(emb + (size_t)bi * Dc);
  float* qx_base = out + O_QX + (size_t)b * Dc * Tc + t;
  float4* ei_base = (float4*)(out + O_EI + (size_t)row * Dc);

  #pragma unroll
  for (int k = 0; k < 16; ++k) {
    float4 ev = eb[k];
    ei_base[k] = ev;
    {
      const int d = 4 * k + 0; float xd = xrow[(size_t)d * Tc];
      float diff = ev.x - xd;
      qx_base[(size_t)d * Tc] = xd + diff;
    }
    {
      const int d = 4 * k + 1; float xd = xrow[(size_t)d * Tc];
      float diff = ev.y - xd;
      qx_base[(size_t)d * Tc] = xd + diff;
    }
    {
      const int d = 4 * k + 2; float xd = xrow[(size_t)d * Tc];
      float diff = ev.z - xd;
      qx_base[(size_t)d * Tc] = xd + diff;
    }
    {
      const int d = 4 * k + 3; float xd = xrow[(size_t)d * Tc];
      float diff = ev.w - xd;
      qx_base[(size_t)d * Tc] = xd + diff;
    }
  }
}

// ---- finalize_a: ema_size update + normalization ----
__global__ __launch_bounds__(1024) void finalize_a(
    const float* __restrict__ ema_size, float* __restrict__ ws,
    float* __restrict__ out) {
  const int e = threadIdx.x;
  float ns = DECAYF * ema_size[e] + OMDF * ws[e];   // counts at ws[0..1024)
  __shared__ float red[1024];
  red[e] = ns;
  __syncthreads();
  for (int s = 512; s > 0; s >>= 1) {
    if (e < s) red[e] += red[e + s];
    __syncthreads();
  }
  float n = red[0];
  float v = ((ns + EPSF) / (n + (float)Ec * EPSF)) * n;
  out[O_ESZ + e] = v;
  ws[66560 + e] = v;                                 // norm
}

// ---- finalize_b: new_ema_w + new_embedding ----
__global__ __launch_bounds__(256) void finalize_b(
    const float* __restrict__ ema_w, const float* __restrict__ ws,
    float* __restrict__ out) {
  int i = blockIdx.x * 256 + threadIdx.x;  // i = d*E + e
  int d = i >> 10;
  int e = i & (Ec - 1);
  float w = DECAYF * ema_w[i] + OMDF * ws[1024 + i];
  out[O_EMW + i] = w;
  out[O_EMB + e * Dc + d] = w / ws[66560 + e];
}

extern "C" void kernel_launch(void* const* d_in, const int* in_sizes, int n_in,
                              void* d_out, int out_size, void* d_ws, size_t ws_size,
                              hipStream_t stream) {
  const float* x        = (const float*)d_in[0];
  const float* emb      = (const float*)d_in[1];
  const float* ema_size = (const float*)d_in[2];
  const float* ema_w    = (const float*)d_in[3];
  float* out = (float*)d_out;
  float* ws  = (float*)d_ws;

  (void)hipMemsetAsync(ws, 0, 1024 * sizeof(float), stream);  // counts only
  decomp_x<<<NROW / 256, 256, 0, stream>>>(x, out);
  decomp_e<<<Ec / 256, 256, 0, stream>>>(emb, out);
  gemm_argmin<<<NROW / 128, 256, 0, stream>>>(out);
  esum_partial<<<dim3(16, 8), 256, 0, stream>>>(out, ws);
  esum_reduce<<<NROW / 256, 256, 0, stream>>>(out, ws);
  epilogue_kernel<<<NROW / 256, 256, 0, stream>>>(x, emb, out);
  finalize_a<<<1, 1024, 0, stream>>>(ema_size, ws, out);
  finalize_b<<<Ec * Dc / 256, 256, 0, stream>>>(ema_w, ws, out);
}

// Round 9
// 214.400 us; speedup vs baseline: 1.2413x; 1.2413x over previous
//
#include <hip/hip_runtime.h>
#include <hip/hip_bf16.h>

constexpr int Bc = 16, Dc = 64, Tc = 4096, Ec = 1024;
constexpr int NROW = Bc * Tc;          // 65536 rows of dim 64
constexpr float DECAYF = 0.99f;
constexpr float OMDF   = 0.01f;
constexpr float EPSF   = 1e-5f;

typedef short bf16x8 __attribute__((ext_vector_type(8)));
typedef float f32x4  __attribute__((ext_vector_type(4)));

// ---- d_out layout (floats, ref return order) ----
constexpr size_t O_EI  = 0;         // embed_idx [B,T,D]   4194304
constexpr size_t O_QX  = 4194304;   // qx [B,D,T]          4194304
constexpr size_t O_IDX = 8388608;   // quantized_idx [B,T]   65536
constexpr size_t O_EMB = 8454144;   // new_embedding [E,D]   65536
constexpr size_t O_ESZ = 8519680;   // new_ema_size [E]       1024
constexpr size_t O_EMW = 8520704;   // new_ema_w [D,E]       65536

// ---- scratch inside d_out's [0, 8388608) floats. Produced by decomp,
// consumed by gemm/esum, only THEN overwritten by the epilogue. ----
constexpr size_t S_XH = 0;          // ushort plane 65536x64 = 2097152 floats
constexpr size_t S_XM = 2097152;
constexpr size_t S_XL = 4194304;
constexpr size_t S_EH = 6291456;    // ushort plane 1024x64 = 32768 floats
constexpr size_t S_EM = 6324224;    // = S_EH + 32768
constexpr size_t S_EL = 6356992;    // = S_EH + 65536
constexpr size_t S_E2 = 6389760;    // 1024 floats
constexpr size_t S_X2 = 6424576;    // 65536 floats (ends 6490112)
constexpr size_t S_P  = 6557696;    // esum partials [16][64][1024] = 1048576

// ---- ws layout (floats): counts[0..1024) | esum[1024..66560) | norm[66560..67584)

__device__ inline unsigned short bf16bits(float v) {
  union { __hip_bfloat16 b; unsigned short u; } c;
  c.b = __float2bfloat16(v);           // RNE
  return c.u;
}
__device__ inline float bf16val(unsigned short u) {
  union { unsigned u32; float f; } c;
  c.u32 = ((unsigned)u) << 16;         // bf16 -> f32 is exact bit expansion
  return c.f;
}
// exact 3-term split: x = h + m + l + eps, |eps| <= 2^-27 |x|
__device__ inline void split3(float x, unsigned short& h, unsigned short& m,
                              unsigned short& l) {
  h = bf16bits(x);
  float r1 = x - bf16val(h);           // exact (Sterbenz)
  m = bf16bits(r1);
  float r2 = r1 - bf16val(m);          // exact
  l = bf16bits(r2);
}

__device__ inline void pack8(unsigned short* s, uint4* dst) {
  uint4 v;
  v.x = (unsigned)s[0] | ((unsigned)s[1] << 16);
  v.y = (unsigned)s[2] | ((unsigned)s[3] << 16);
  v.z = (unsigned)s[4] | ((unsigned)s[5] << 16);
  v.w = (unsigned)s[6] | ((unsigned)s[7] << 16);
  *dst = v;
}

__device__ inline void gl_lds16(const unsigned short* g, unsigned short* l) {
  __builtin_amdgcn_global_load_lds(
      (const __attribute__((address_space(1))) void*)g,
      (__attribute__((address_space(3))) void*)l, 16, 0, 0);
}

// ---- decomp_x: lane=row; coalesced x read; x2 (exact np-pairwise); 3 planes ----
__global__ __launch_bounds__(256) void decomp_x(const float* __restrict__ x,
                                                float* __restrict__ out) {
  const int row = blockIdx.x * 256 + threadIdx.x;
  const int b = row >> 12, t = row & (Tc - 1);
  const float* xrow = x + (size_t)b * Dc * Tc + t;
  float xv[64];
  #pragma unroll
  for (int d = 0; d < Dc; ++d) xv[d] = xrow[(size_t)d * Tc];

  float x2;
  {
    #pragma clang fp contract(off)
    float r[8];
    #pragma unroll
    for (int j = 0; j < 8; ++j) r[j] = xv[j] * xv[j];
    #pragma unroll
    for (int k = 1; k < 8; ++k) {
      #pragma unroll
      for (int j = 0; j < 8; ++j) r[j] += xv[8 * k + j] * xv[8 * k + j];
    }
    x2 = ((r[0] + r[1]) + (r[2] + r[3])) + ((r[4] + r[5]) + (r[6] + r[7]));
  }
  out[S_X2 + row] = x2;

  uint4* ph = (uint4*)((unsigned short*)(out + S_XH) + (size_t)row * 64);
  uint4* pm = (uint4*)((unsigned short*)(out + S_XM) + (size_t)row * 64);
  uint4* pl = (uint4*)((unsigned short*)(out + S_XL) + (size_t)row * 64);
  #pragma unroll
  for (int k = 0; k < 8; ++k) {
    unsigned short hs[8], ms[8], ls[8];
    #pragma unroll
    for (int j = 0; j < 8; ++j) split3(xv[8 * k + j], hs[j], ms[j], ls[j]);
    pack8(hs, ph + k); pack8(ms, pm + k); pack8(ls, pl + k);
  }
}

// ---- decomp_e: thread=codeword; e2 (exact np-pairwise); 3 planes ----
__global__ __launch_bounds__(256) void decomp_e(const float* __restrict__ emb,
                                                float* __restrict__ out) {
  const int c = blockIdx.x * 256 + threadIdx.x;
  if (c >= Ec) return;
  const float* ep = emb + (size_t)c * Dc;
  float ev[64];
  #pragma unroll
  for (int d = 0; d < Dc; ++d) ev[d] = ep[d];

  float e2;
  {
    #pragma clang fp contract(off)
    float r[8];
    #pragma unroll
    for (int j = 0; j < 8; ++j) r[j] = ev[j] * ev[j];
    #pragma unroll
    for (int k = 1; k < 8; ++k) {
      #pragma unroll
      for (int j = 0; j < 8; ++j) r[j] += ev[8 * k + j] * ev[8 * k + j];
    }
    e2 = ((r[0] + r[1]) + (r[2] + r[3])) + ((r[4] + r[5]) + (r[6] + r[7]));
  }
  out[S_E2 + c] = e2;

  uint4* ph = (uint4*)((unsigned short*)(out + S_EH) + (size_t)c * 64);
  uint4* pm = (uint4*)((unsigned short*)(out + S_EM) + (size_t)c * 64);
  uint4* pl = (uint4*)((unsigned short*)(out + S_EL) + (size_t)c * 64);
  #pragma unroll
  for (int k = 0; k < 8; ++k) {
    unsigned short hs[8], ms[8], ls[8];
    #pragma unroll
    for (int j = 0; j < 8; ++j) split3(ev[8 * k + j], hs[j], ms[j], ls[j]);
    pack8(hs, ph + k); pack8(ms, pm + k); pack8(ls, pl + k);
  }
}

// ---- gemm_argmin: 512 threads = 8 waves x 32 rows; all waves scan all 1024
// cw. B staged in LDS, FRAGMENT-MAJOR layout [nt][plane][half][lane][16B]
// (lane-consecutive ds_read_b128 -> conflict-free; cw-major would be 16-way
// conflicted). R8 lesson: allocator remats read-only global loads regardless
// of VGPR budget -> B must live in LDS so reloads are cheap. ----
constexpr int TW = 64;              // cw per tile; 16 tiles
constexpr int SLOTS = (TW / 16) * 3 * 2 * 64;  // 16B slots per tile = 1536

__global__ __launch_bounds__(512)
__attribute__((amdgpu_waves_per_eu(2, 2)))
void gemm_argmin(float* __restrict__ out) {
  __shared__ alignas(16) unsigned short lbuf[2][SLOTS * 8];  // 2 x 24 KB

  const int tid  = threadIdx.x;       // 0..511
  const int lane = tid & 63;
  const int wave = tid >> 6;          // 0..7
  const int col  = lane & 15;         // MFMA n / C-col
  const int quad = lane >> 4;
  const int rowbase = blockIdx.x * 256 + wave * 32;

  const unsigned short* XH = (const unsigned short*)(out + S_XH);
  const unsigned short* XM = (const unsigned short*)(out + S_XM);
  const unsigned short* XL = (const unsigned short*)(out + S_XL);
  const unsigned short* EHu = (const unsigned short*)(out + S_EH);
  const float* E2 = out + S_E2;
  const float* X2 = out + S_X2;

  // stage tile tl into lbuf[s]: slot = ((nt*3+pl)*2+half)*64 + lane
  auto stage = [&](int tl, int s) {
    #pragma unroll
    for (int i = 0; i < 3; ++i) {
      int slot = tid + i * 512;       // 0..1535
      int sl   = slot & 63;
      int sub  = slot >> 6;           // 0..23
      int half = sub & 1;
      int pl   = (sub >> 1) % 3;
      int nt   = sub / 6;             // 0..3
      int cw   = tl * TW + nt * 16 + (sl & 15);
      int q    = sl >> 4;
      const unsigned short* src =
          EHu + (size_t)pl * 65536 + (size_t)cw * 64 + half * 32 + q * 8;
      gl_lds16(src, &lbuf[s][(size_t)slot * 8]);
    }
  };

  bf16x8 a[12];                       // A-frags: a[mt*6 + plane*2 + half]
  #pragma unroll
  for (int mt = 0; mt < 2; ++mt) {
    size_t ao = (size_t)(rowbase + mt * 16 + col) * 64 + quad * 8;
    a[mt * 6 + 0] = *(const bf16x8*)(XH + ao);
    a[mt * 6 + 1] = *(const bf16x8*)(XH + ao + 32);
    a[mt * 6 + 2] = *(const bf16x8*)(XM + ao);
    a[mt * 6 + 3] = *(const bf16x8*)(XM + ao + 32);
    a[mt * 6 + 4] = *(const bf16x8*)(XL + ao);
    a[mt * 6 + 5] = *(const bf16x8*)(XL + ao + 32);
  }
  float x2v[8];
  #pragma unroll
  for (int mt = 0; mt < 2; ++mt)
    #pragma unroll
    for (int r = 0; r < 4; ++r)
      x2v[mt * 4 + r] = X2[rowbase + mt * 16 + quad * 4 + r];

  float best[8];
  int bidx[8];
  #pragma unroll
  for (int i = 0; i < 8; ++i) { best[i] = 3.4e38f; bidx[i] = 0; }

  stage(0, 0);

  for (int tl = 0; tl < Ec / TW; ++tl) {
    __syncthreads();                   // stage(tl) complete (implicit vmcnt drain)
    if (tl + 1 < Ec / TW) stage(tl + 1, (tl + 1) & 1);
    const unsigned short* lb = lbuf[tl & 1];

    #pragma unroll
    for (int nt4 = 0; nt4 < TW / 16; ++nt4) {
      bf16x8 bb[6];
      #pragma unroll
      for (int pl = 0; pl < 3; ++pl)
        #pragma unroll
        for (int h = 0; h < 2; ++h)
          bb[pl * 2 + h] = *(const bf16x8*)(
              lb + ((size_t)(((nt4 * 3 + pl) * 2 + h) * 64 + lane)) * 8);
      const float e2v = E2[tl * TW + nt4 * 16 + col];

      f32x4 acc0 = {0.f, 0.f, 0.f, 0.f};
      f32x4 acc1 = {0.f, 0.f, 0.f, 0.f};
      const int PA[6] = {0, 0, 1, 1, 0, 2};   // products hh,hm,mh,mm,hl,lh
      const int PB[6] = {0, 1, 0, 1, 2, 0};
      #pragma unroll
      for (int p = 0; p < 6; ++p) {
        #pragma unroll
        for (int s = 0; s < 2; ++s) {
          bf16x8 bf = bb[PB[p] * 2 + s];
          acc0 = __builtin_amdgcn_mfma_f32_16x16x32_bf16(a[PA[p] * 2 + s], bf, acc0, 0, 0, 0);
          acc1 = __builtin_amdgcn_mfma_f32_16x16x32_bf16(a[6 + PA[p] * 2 + s], bf, acc1, 0, 0, 0);
        }
      }

      const int cwv = tl * TW + nt4 * 16 + col;
      #pragma unroll
      for (int r = 0; r < 4; ++r) {
        {
          float q = __builtin_fmaf(-2.0f, acc0[r], e2v);  // fl(e2 - 2*dot)
          q = q + x2v[r];                                  // fl(+ x2)
          if (q < best[r]) { best[r] = q; bidx[r] = cwv; }
        }
        {
          float q = __builtin_fmaf(-2.0f, acc1[r], e2v);
          q = q + x2v[4 + r];
          if (q < best[4 + r]) { best[4 + r] = q; bidx[4 + r] = cwv; }
        }
      }
    }
  }

  // cross-lane argmin within each 16-lane col group (ties -> lowest cw index)
  #pragma unroll
  for (int i = 0; i < 8; ++i) {
    float bq = best[i];
    int bi = bidx[i];
    #pragma unroll
    for (int m = 1; m <= 8; m <<= 1) {
      float qo = __shfl_xor(bq, m, 64);
      int io = __shfl_xor(bi, m, 64);
      bool take = (qo < bq) || (qo == bq && io < bi);
      bq = take ? qo : bq;
      bi = take ? io : bi;
    }
    if (col == 0) {
      int mt = i >> 2, r = i & 3;
      int row = rowbase + mt * 16 + quad * 4 + r;
      out[O_IDX + row] = (float)bi;   // C row = quad*4+reg [m89]
    }
  }
}

// ---- esum_partial: segmented reduction of x into embed_sum via LDS. ----
__global__ __launch_bounds__(256) void esum_partial(float* __restrict__ out,
                                                    float* __restrict__ ws) {
  const int c = blockIdx.x;       // row chunk, 4096 rows
  const int s = blockIdx.y;       // d-slice of 8
  __shared__ float acc[8 * 1024];
  __shared__ float cnt[1024];
  for (int i = threadIdx.x; i < 8192; i += 256) acc[i] = 0.f;
  if (s == 0)
    for (int i = threadIdx.x; i < 1024; i += 256) cnt[i] = 0.f;
  __syncthreads();

  const unsigned short* XH = (const unsigned short*)(out + S_XH);
  const unsigned short* XM = (const unsigned short*)(out + S_XM);
  const unsigned short* XL = (const unsigned short*)(out + S_XL);

  for (int it = 0; it < 16; ++it) {
    const int r = c * 4096 + it * 256 + threadIdx.x;
    const int bi = (int)out[O_IDX + r];
    const size_t off = (size_t)r * 64 + s * 8;
    const uint4 h = *(const uint4*)(XH + off);
    const uint4 m = *(const uint4*)(XM + off);
    const uint4 l = *(const uint4*)(XL + off);

#define DOPAIR(k, HW, MW, LW)                                                  \
    {                                                                          \
      float v0 = (bf16val((unsigned short)(HW)) +                              \
                  bf16val((unsigned short)(MW))) +                             \
                 bf16val((unsigned short)(LW));                                \
      float v1 = (bf16val((unsigned short)((HW) >> 16)) +                      \
                  bf16val((unsigned short)((MW) >> 16))) +                     \
                 bf16val((unsigned short)((LW) >> 16));                        \
      atomicAdd(&acc[(2 * (k) + 0) * 1024 + bi], v0);                          \
      atomicAdd(&acc[(2 * (k) + 1) * 1024 + bi], v1);                          \
    }
    DOPAIR(0, h.x, m.x, l.x)
    DOPAIR(1, h.y, m.y, l.y)
    DOPAIR(2, h.z, m.z, l.z)
    DOPAIR(3, h.w, m.w, l.w)
#undef DOPAIR
    if (s == 0) atomicAdd(&cnt[bi], 1.0f);
  }
  __syncthreads();

  float* part = out + S_P + ((size_t)c * 64 + s * 8) * 1024;
  for (int i = threadIdx.x; i < 8192; i += 256) part[i] = acc[i];
  if (s == 0)
    for (int i = threadIdx.x; i < 1024; i += 256)
      atomicAdd(&ws[i], cnt[i]);
}

// ---- esum_reduce: esum[i] = sum over 16 chunk partials ----
__global__ __launch_bounds__(256) void esum_reduce(const float* __restrict__ out,
                                                   float* __restrict__ ws) {
  const int i = blockIdx.x * 256 + threadIdx.x;  // 0..65535 (= d*1024+e)
  float v = 0.f;
  #pragma unroll
  for (int c = 0; c < 16; ++c) v += out[S_P + (size_t)c * 65536 + i];
  ws[1024 + i] = v;
}

// ---- epilogue: pure streaming: read x/idx, gather emb, write embed_idx+qx ----
__global__ __launch_bounds__(256) void epilogue_kernel(
    const float* __restrict__ x, const float* __restrict__ emb,
    float* __restrict__ out) {
  const int row = blockIdx.x * 256 + threadIdx.x;
  const int b = row >> 12, t = row & (Tc - 1);
  const float* xrow = x + (size_t)b * Dc * Tc + t;

  const int bi = (int)out[O_IDX + row];

  const float4* eb = (const float4*)(emb + (size_t)bi * Dc);
  float* qx_base = out + O_QX + (size_t)b * Dc * Tc + t;
  float4* ei_base = (float4*)(out + O_EI + (size_t)row * Dc);

  #pragma unroll
  for (int k = 0; k < 16; ++k) {
    float4 ev = eb[k];
    ei_base[k] = ev;
    {
      const int d = 4 * k + 0; float xd = xrow[(size_t)d * Tc];
      float diff = ev.x - xd;
      qx_base[(size_t)d * Tc] = xd + diff;
    }
    {
      const int d = 4 * k + 1; float xd = xrow[(size_t)d * Tc];
      float diff = ev.y - xd;
      qx_base[(size_t)d * Tc] = xd + diff;
    }
    {
      const int d = 4 * k + 2; float xd = xrow[(size_t)d * Tc];
      float diff = ev.z - xd;
      qx_base[(size_t)d * Tc] = xd + diff;
    }
    {
      const int d = 4 * k + 3; float xd = xrow[(size_t)d * Tc];
      float diff = ev.w - xd;
      qx_base[(size_t)d * Tc] = xd + diff;
    }
  }
}

// ---- finalize_a: ema_size update + normalization ----
__global__ __launch_bounds__(1024) void finalize_a(
    const float* __restrict__ ema_size, float* __restrict__ ws,
    float* __restrict__ out) {
  const int e = threadIdx.x;
  float ns = DECAYF * ema_size[e] + OMDF * ws[e];
  __shared__ float red[1024];
  red[e] = ns;
  __syncthreads();
  for (int s = 512; s > 0; s >>= 1) {
    if (e < s) red[e] += red[e + s];
    __syncthreads();
  }
  float n = red[0];
  float v = ((ns + EPSF) / (n + (float)Ec * EPSF)) * n;
  out[O_ESZ + e] = v;
  ws[66560 + e] = v;
}

// ---- finalize_b: new_ema_w + new_embedding ----
__global__ __launch_bounds__(256) void finalize_b(
    const float* __restrict__ ema_w, const float* __restrict__ ws,
    float* __restrict__ out) {
  int i = blockIdx.x * 256 + threadIdx.x;  // i = d*E + e
  int d = i >> 10;
  int e = i & (Ec - 1);
  float w = DECAYF * ema_w[i] + OMDF * ws[1024 + i];
  out[O_EMW + i] = w;
  out[O_EMB + e * Dc + d] = w / ws[66560 + e];
}

extern "C" void kernel_launch(void* const* d_in, const int* in_sizes, int n_in,
                              void* d_out, int out_size, void* d_ws, size_t ws_size,
                              hipStream_t stream) {
  const float* x        = (const float*)d_in[0];
  const float* emb      = (const float*)d_in[1];
  const float* ema_size = (const float*)d_in[2];
  const float* ema_w    = (const float*)d_in[3];
  float* out = (float*)d_out;
  float* ws  = (float*)d_ws;

  (void)hipMemsetAsync(ws, 0, 1024 * sizeof(float), stream);  // counts only
  decomp_x<<<NROW / 256, 256, 0, stream>>>(x, out);
  decomp_e<<<Ec / 256, 256, 0, stream>>>(emb, out);
  gemm_argmin<<<256, 512, 0, stream>>>(out);
  esum_partial<<<dim3(16, 8), 256, 0, stream>>>(out, ws);
  esum_reduce<<<NROW / 256, 256, 0, stream>>>(out, ws);
  epilogue_kernel<<<NROW / 256, 256, 0, stream>>>(x, emb, out);
  finalize_a<<<1, 1024, 0, stream>>>(ema_size, ws, out);
  finalize_b<<<Ec * Dc / 256, 256, 0, stream>>>(ema_w, ws, out);
}

// Round 10
// 192.581 us; speedup vs baseline: 1.3820x; 1.1133x over previous
//
#include <hip/hip_runtime.h>
#include <hip/hip_bf16.h>

constexpr int Bc = 16, Dc = 64, Tc = 4096, Ec = 1024;
constexpr int NROW = Bc * Tc;          // 65536 rows of dim 64
constexpr float DECAYF = 0.99f;
constexpr float OMDF   = 0.01f;
constexpr float EPSF   = 1e-5f;

typedef short bf16x8 __attribute__((ext_vector_type(8)));
typedef float f32x4  __attribute__((ext_vector_type(4)));

// ---- d_out layout (floats, ref return order) ----
constexpr size_t O_EI  = 0;         // embed_idx [B,T,D]   4194304
constexpr size_t O_QX  = 4194304;   // qx [B,D,T]          4194304
constexpr size_t O_IDX = 8388608;   // quantized_idx [B,T]   65536
constexpr size_t O_EMB = 8454144;   // new_embedding [E,D]   65536
constexpr size_t O_ESZ = 8519680;   // new_ema_size [E]       1024
constexpr size_t O_EMW = 8520704;   // new_ema_w [D,E]       65536

// ---- scratch inside d_out's [0, 8388608) floats. Produced by decomp,
// consumed by gemm/esum, only THEN overwritten by the epilogue. ----
constexpr size_t S_XH = 0;          // ushort plane 65536x64 = 2097152 floats
constexpr size_t S_XM = 2097152;
constexpr size_t S_XL = 4194304;
constexpr size_t S_EH = 6291456;    // ushort plane 1024x64 = 32768 floats
constexpr size_t S_EM = 6324224;    // = S_EH + 32768
constexpr size_t S_EL = 6356992;    // = S_EH + 65536
constexpr size_t S_E2 = 6389760;    // 1024 floats
constexpr size_t S_X2 = 6424576;    // 65536 floats (ends 6490112)
constexpr size_t S_P  = 6557696;    // esum partials [16][64][1024] = 1048576

// ---- ws layout (floats): counts[0..1024) | esum[1024..66560) | norm[66560..67584)

__device__ inline unsigned short bf16bits(float v) {
  union { __hip_bfloat16 b; unsigned short u; } c;
  c.b = __float2bfloat16(v);           // RNE
  return c.u;
}
__device__ inline float bf16val(unsigned short u) {
  union { unsigned u32; float f; } c;
  c.u32 = ((unsigned)u) << 16;         // bf16 -> f32 is exact bit expansion
  return c.f;
}
// exact 3-term split: x = h + m + l + eps, |eps| <= 2^-27 |x|
__device__ inline void split3(float x, unsigned short& h, unsigned short& m,
                              unsigned short& l) {
  h = bf16bits(x);
  float r1 = x - bf16val(h);           // exact (Sterbenz)
  m = bf16bits(r1);
  float r2 = r1 - bf16val(m);          // exact
  l = bf16bits(r2);
}

__device__ inline void pack8(unsigned short* s, uint4* dst) {
  uint4 v;
  v.x = (unsigned)s[0] | ((unsigned)s[1] << 16);
  v.y = (unsigned)s[2] | ((unsigned)s[3] << 16);
  v.z = (unsigned)s[4] | ((unsigned)s[5] << 16);
  v.w = (unsigned)s[6] | ((unsigned)s[7] << 16);
  *dst = v;
}

__device__ inline void gl_lds16(const unsigned short* g, unsigned short* l) {
  __builtin_amdgcn_global_load_lds(
      (const __attribute__((address_space(1))) void*)g,
      (__attribute__((address_space(3))) void*)l, 16, 0, 0);
}

// ---- decomp_x: lane=row; coalesced x read; x2 (exact np-pairwise); 3 planes ----
__global__ __launch_bounds__(256) void decomp_x(const float* __restrict__ x,
                                                float* __restrict__ out) {
  const int row = blockIdx.x * 256 + threadIdx.x;
  const int b = row >> 12, t = row & (Tc - 1);
  const float* xrow = x + (size_t)b * Dc * Tc + t;
  float xv[64];
  #pragma unroll
  for (int d = 0; d < Dc; ++d) xv[d] = xrow[(size_t)d * Tc];

  float x2;
  {
    #pragma clang fp contract(off)
    float r[8];
    #pragma unroll
    for (int j = 0; j < 8; ++j) r[j] = xv[j] * xv[j];
    #pragma unroll
    for (int k = 1; k < 8; ++k) {
      #pragma unroll
      for (int j = 0; j < 8; ++j) r[j] += xv[8 * k + j] * xv[8 * k + j];
    }
    x2 = ((r[0] + r[1]) + (r[2] + r[3])) + ((r[4] + r[5]) + (r[6] + r[7]));
  }
  out[S_X2 + row] = x2;

  uint4* ph = (uint4*)((unsigned short*)(out + S_XH) + (size_t)row * 64);
  uint4* pm = (uint4*)((unsigned short*)(out + S_XM) + (size_t)row * 64);
  uint4* pl = (uint4*)((unsigned short*)(out + S_XL) + (size_t)row * 64);
  #pragma unroll
  for (int k = 0; k < 8; ++k) {
    unsigned short hs[8], ms[8], ls[8];
    #pragma unroll
    for (int j = 0; j < 8; ++j) split3(xv[8 * k + j], hs[j], ms[j], ls[j]);
    pack8(hs, ph + k); pack8(ms, pm + k); pack8(ls, pl + k);
  }
}

// ---- decomp_e: thread=codeword; e2 (exact np-pairwise); 3 planes ----
__global__ __launch_bounds__(256) void decomp_e(const float* __restrict__ emb,
                                                float* __restrict__ out) {
  const int c = blockIdx.x * 256 + threadIdx.x;
  if (c >= Ec) return;
  const float* ep = emb + (size_t)c * Dc;
  float ev[64];
  #pragma unroll
  for (int d = 0; d < Dc; ++d) ev[d] = ep[d];

  float e2;
  {
    #pragma clang fp contract(off)
    float r[8];
    #pragma unroll
    for (int j = 0; j < 8; ++j) r[j] = ev[j] * ev[j];
    #pragma unroll
    for (int k = 1; k < 8; ++k) {
      #pragma unroll
      for (int j = 0; j < 8; ++j) r[j] += ev[8 * k + j] * ev[8 * k + j];
    }
    e2 = ((r[0] + r[1]) + (r[2] + r[3])) + ((r[4] + r[5]) + (r[6] + r[7]));
  }
  out[S_E2 + c] = e2;

  uint4* ph = (uint4*)((unsigned short*)(out + S_EH) + (size_t)c * 64);
  uint4* pm = (uint4*)((unsigned short*)(out + S_EM) + (size_t)c * 64);
  uint4* pl = (uint4*)((unsigned short*)(out + S_EL) + (size_t)c * 64);
  #pragma unroll
  for (int k = 0; k < 8; ++k) {
    unsigned short hs[8], ms[8], ls[8];
    #pragma unroll
    for (int j = 0; j < 8; ++j) split3(ev[8 * k + j], hs[j], ms[j], ls[j]);
    pack8(hs, ph + k); pack8(ms, pm + k); pack8(ls, pl + k);
  }
}

// ---- gemm_argmin: 512 threads = 8 waves x 32 rows; all waves scan all 1024
// cw. B staged in LDS, FRAGMENT-MAJOR layout [nt][plane][half][lane][16B]
// (lane-consecutive ds_read_b128 -> conflict-free). ----
constexpr int TW = 64;              // cw per tile; 16 tiles
constexpr int SLOTS = (TW / 16) * 3 * 2 * 64;  // 16B slots per tile = 1536

__global__ __launch_bounds__(512)
__attribute__((amdgpu_waves_per_eu(2, 2)))
void gemm_argmin(float* __restrict__ out) {
  __shared__ alignas(16) unsigned short lbuf[2][SLOTS * 8];  // 2 x 24 KB

  const int tid  = threadIdx.x;       // 0..511
  const int lane = tid & 63;
  const int wave = tid >> 6;          // 0..7
  const int col  = lane & 15;         // MFMA n / C-col
  const int quad = lane >> 4;
  const int rowbase = blockIdx.x * 256 + wave * 32;

  const unsigned short* XH = (const unsigned short*)(out + S_XH);
  const unsigned short* XM = (const unsigned short*)(out + S_XM);
  const unsigned short* XL = (const unsigned short*)(out + S_XL);
  const unsigned short* EHu = (const unsigned short*)(out + S_EH);
  const float* E2 = out + S_E2;
  const float* X2 = out + S_X2;

  // stage tile tl into lbuf[s]: slot = ((nt*3+pl)*2+half)*64 + lane
  auto stage = [&](int tl, int s) {
    #pragma unroll
    for (int i = 0; i < 3; ++i) {
      int slot = tid + i * 512;       // 0..1535
      int sl   = slot & 63;
      int sub  = slot >> 6;           // 0..23
      int half = sub & 1;
      int pl   = (sub >> 1) % 3;
      int nt   = sub / 6;             // 0..3
      int cw   = tl * TW + nt * 16 + (sl & 15);
      int q    = sl >> 4;
      const unsigned short* src =
          EHu + (size_t)pl * 65536 + (size_t)cw * 64 + half * 32 + q * 8;
      gl_lds16(src, &lbuf[s][(size_t)slot * 8]);
    }
  };

  bf16x8 a[12];                       // A-frags: a[mt*6 + plane*2 + half]
  #pragma unroll
  for (int mt = 0; mt < 2; ++mt) {
    size_t ao = (size_t)(rowbase + mt * 16 + col) * 64 + quad * 8;
    a[mt * 6 + 0] = *(const bf16x8*)(XH + ao);
    a[mt * 6 + 1] = *(const bf16x8*)(XH + ao + 32);
    a[mt * 6 + 2] = *(const bf16x8*)(XM + ao);
    a[mt * 6 + 3] = *(const bf16x8*)(XM + ao + 32);
    a[mt * 6 + 4] = *(const bf16x8*)(XL + ao);
    a[mt * 6 + 5] = *(const bf16x8*)(XL + ao + 32);
  }
  float x2v[8];
  #pragma unroll
  for (int mt = 0; mt < 2; ++mt)
    #pragma unroll
    for (int r = 0; r < 4; ++r)
      x2v[mt * 4 + r] = X2[rowbase + mt * 16 + quad * 4 + r];

  float best[8];
  int bidx[8];
  #pragma unroll
  for (int i = 0; i < 8; ++i) { best[i] = 3.4e38f; bidx[i] = 0; }

  stage(0, 0);

  for (int tl = 0; tl < Ec / TW; ++tl) {
    __syncthreads();                   // stage(tl) complete (implicit vmcnt drain)
    if (tl + 1 < Ec / TW) stage(tl + 1, (tl + 1) & 1);
    const unsigned short* lb = lbuf[tl & 1];

    #pragma unroll
    for (int nt4 = 0; nt4 < TW / 16; ++nt4) {
      bf16x8 bb[6];
      #pragma unroll
      for (int pl = 0; pl < 3; ++pl)
        #pragma unroll
        for (int h = 0; h < 2; ++h)
          bb[pl * 2 + h] = *(const bf16x8*)(
              lb + ((size_t)(((nt4 * 3 + pl) * 2 + h) * 64 + lane)) * 8);
      const float e2v = E2[tl * TW + nt4 * 16 + col];

      f32x4 acc0 = {0.f, 0.f, 0.f, 0.f};
      f32x4 acc1 = {0.f, 0.f, 0.f, 0.f};
      const int PA[6] = {0, 0, 1, 1, 0, 2};   // products hh,hm,mh,mm,hl,lh
      const int PB[6] = {0, 1, 0, 1, 2, 0};
      #pragma unroll
      for (int p = 0; p < 6; ++p) {
        #pragma unroll
        for (int s = 0; s < 2; ++s) {
          bf16x8 bf = bb[PB[p] * 2 + s];
          acc0 = __builtin_amdgcn_mfma_f32_16x16x32_bf16(a[PA[p] * 2 + s], bf, acc0, 0, 0, 0);
          acc1 = __builtin_amdgcn_mfma_f32_16x16x32_bf16(a[6 + PA[p] * 2 + s], bf, acc1, 0, 0, 0);
        }
      }

      const int cwv = tl * TW + nt4 * 16 + col;
      #pragma unroll
      for (int r = 0; r < 4; ++r) {
        {
          float q = __builtin_fmaf(-2.0f, acc0[r], e2v);  // fl(e2 - 2*dot)
          q = q + x2v[r];                                  // fl(+ x2)
          if (q < best[r]) { best[r] = q; bidx[r] = cwv; }
        }
        {
          float q = __builtin_fmaf(-2.0f, acc1[r], e2v);
          q = q + x2v[4 + r];
          if (q < best[4 + r]) { best[4 + r] = q; bidx[4 + r] = cwv; }
        }
      }
    }
  }

  // cross-lane argmin within each 16-lane col group (ties -> lowest cw index)
  #pragma unroll
  for (int i = 0; i < 8; ++i) {
    float bq = best[i];
    int bi = bidx[i];
    #pragma unroll
    for (int m = 1; m <= 8; m <<= 1) {
      float qo = __shfl_xor(bq, m, 64);
      int io = __shfl_xor(bi, m, 64);
      bool take = (qo < bq) || (qo == bq && io < bi);
      bq = take ? qo : bq;
      bi = take ? io : bi;
    }
    if (col == 0) {
      int mt = i >> 2, r = i & 3;
      int row = rowbase + mt * 16 + quad * 4 + r;
      out[O_IDX + row] = (float)bi;   // C row = quad*4+reg [m89]
    }
  }
}

// ---- esum_partial: segmented reduction of x into embed_sum via LDS.
// R9 lesson: 16x8 grid = 128 blocks / 4 waves = half the GPU idle at 4.6%
// occupancy -> latency-naked serial chains. Now 16 chunks x 16 slices (4 d
// each) = 256 blocks x 512 threads (8 waves/CU), 8 iters. acc stride 1025:
// a thread's 4 atomics hit 4 consecutive banks (1025 = 1 mod 32) instead of
// all landing in bank bi&31 (1024 = 0 mod 32). ----
__global__ __launch_bounds__(512) void esum_partial(float* __restrict__ out,
                                                    float* __restrict__ ws) {
  const int c = blockIdx.x;       // row chunk, 4096 rows
  const int s = blockIdx.y;       // d-slice of 4
  __shared__ float acc[4 * 1025];
  __shared__ float cnt[1024];
  for (int i = threadIdx.x; i < 4 * 1025; i += 512) acc[i] = 0.f;
  if (s == 0)
    for (int i = threadIdx.x; i < 1024; i += 512) cnt[i] = 0.f;
  __syncthreads();

  const unsigned short* XH = (const unsigned short*)(out + S_XH);
  const unsigned short* XM = (const unsigned short*)(out + S_XM);
  const unsigned short* XL = (const unsigned short*)(out + S_XL);

  #pragma unroll 2
  for (int it = 0; it < 8; ++it) {
    const int r = c * 4096 + it * 512 + threadIdx.x;
    const int bi = (int)out[O_IDX + r];
    const size_t off = (size_t)r * 64 + s * 4;
    const uint2 h = *(const uint2*)(XH + off);
    const uint2 m = *(const uint2*)(XM + off);
    const uint2 l = *(const uint2*)(XL + off);

#define DOPAIR(k, HW, MW, LW)                                                  \
    {                                                                          \
      float v0 = (bf16val((unsigned short)(HW)) +                              \
                  bf16val((unsigned short)(MW))) +                             \
                 bf16val((unsigned short)(LW));                                \
      float v1 = (bf16val((unsigned short)((HW) >> 16)) +                      \
                  bf16val((unsigned short)((MW) >> 16))) +                     \
                 bf16val((unsigned short)((LW) >> 16));                        \
      atomicAdd(&acc[(2 * (k) + 0) * 1025 + bi], v0);                          \
      atomicAdd(&acc[(2 * (k) + 1) * 1025 + bi], v1);                          \
    }
    DOPAIR(0, h.x, m.x, l.x)
    DOPAIR(1, h.y, m.y, l.y)
#undef DOPAIR
    if (s == 0) atomicAdd(&cnt[bi], 1.0f);
  }
  __syncthreads();

  float* part = out + S_P + ((size_t)c * 64 + s * 4) * 1024;
  for (int i = threadIdx.x; i < 4096; i += 512)
    part[i] = acc[(i >> 10) * 1025 + (i & 1023)];
  if (s == 0)
    for (int i = threadIdx.x; i < 1024; i += 512)
      atomicAdd(&ws[i], cnt[i]);
}

// ---- esum_reduce: esum[i] = sum over 16 chunk partials ----
__global__ __launch_bounds__(256) void esum_reduce(const float* __restrict__ out,
                                                   float* __restrict__ ws) {
  const int i = blockIdx.x * 256 + threadIdx.x;  // 0..65535 (= d*1024+e)
  float v = 0.f;
  #pragma unroll
  for (int c = 0; c < 16; ++c) v += out[S_P + (size_t)c * 65536 + i];
  ws[1024 + i] = v;
}

// ---- epilogue: pure streaming: read x/idx, gather emb, write embed_idx+qx ----
__global__ __launch_bounds__(256) void epilogue_kernel(
    const float* __restrict__ x, const float* __restrict__ emb,
    float* __restrict__ out) {
  const int row = blockIdx.x * 256 + threadIdx.x;
  const int b = row >> 12, t = row & (Tc - 1);
  const float* xrow = x + (size_t)b * Dc * Tc + t;

  const int bi = (int)out[O_IDX + row];

  const float4* eb = (const float4*)(emb + (size_t)bi * Dc);
  float* qx_base = out + O_QX + (size_t)b * Dc * Tc + t;
  float4* ei_base = (float4*)(out + O_EI + (size_t)row * Dc);

  #pragma unroll
  for (int k = 0; k < 16; ++k) {
    float4 ev = eb[k];
    ei_base[k] = ev;
    {
      const int d = 4 * k + 0; float xd = xrow[(size_t)d * Tc];
      float diff = ev.x - xd;
      qx_base[(size_t)d * Tc] = xd + diff;
    }
    {
      const int d = 4 * k + 1; float xd = xrow[(size_t)d * Tc];
      float diff = ev.y - xd;
      qx_base[(size_t)d * Tc] = xd + diff;
    }
    {
      const int d = 4 * k + 2; float xd = xrow[(size_t)d * Tc];
      float diff = ev.z - xd;
      qx_base[(size_t)d * Tc] = xd + diff;
    }
    {
      const int d = 4 * k + 3; float xd = xrow[(size_t)d * Tc];
      float diff = ev.w - xd;
      qx_base[(size_t)d * Tc] = xd + diff;
    }
  }
}

// ---- finalize_a: ema_size update + normalization ----
__global__ __launch_bounds__(1024) void finalize_a(
    const float* __restrict__ ema_size, float* __restrict__ ws,
    float* __restrict__ out) {
  const int e = threadIdx.x;
  float ns = DECAYF * ema_size[e] + OMDF * ws[e];
  __shared__ float red[1024];
  red[e] = ns;
  __syncthreads();
  for (int s = 512; s > 0; s >>= 1) {
    if (e < s) red[e] += red[e + s];
    __syncthreads();
  }
  float n = red[0];
  float v = ((ns + EPSF) / (n + (float)Ec * EPSF)) * n;
  out[O_ESZ + e] = v;
  ws[66560 + e] = v;
}

// ---- finalize_b: new_ema_w + new_embedding ----
__global__ __launch_bounds__(256) void finalize_b(
    const float* __restrict__ ema_w, const float* __restrict__ ws,
    float* __restrict__ out) {
  int i = blockIdx.x * 256 + threadIdx.x;  // i = d*E + e
  int d = i >> 10;
  int e = i & (Ec - 1);
  float w = DECAYF * ema_w[i] + OMDF * ws[1024 + i];
  out[O_EMW + i] = w;
  out[O_EMB + e * Dc + d] = w / ws[66560 + e];
}

extern "C" void kernel_launch(void* const* d_in, const int* in_sizes, int n_in,
                              void* d_out, int out_size, void* d_ws, size_t ws_size,
                              hipStream_t stream) {
  const float* x        = (const float*)d_in[0];
  const float* emb      = (const float*)d_in[1];
  const float* ema_size = (const float*)d_in[2];
  const float* ema_w    = (const float*)d_in[3];
  float* out = (float*)d_out;
  float* ws  = (float*)d_ws;

  (void)hipMemsetAsync(ws, 0, 1024 * sizeof(float), stream);  // counts only
  decomp_x<<<NROW / 256, 256, 0, stream>>>(x, out);
  decomp_e<<<Ec / 256, 256, 0, stream>>>(emb, out);
  gemm_argmin<<<256, 512, 0, stream>>>(out);
  esum_partial<<<dim3(16, 16), 512, 0, stream>>>(out, ws);
  esum_reduce<<<NROW / 256, 256, 0, stream>>>(out, ws);
  epilogue_kernel<<<NROW / 256, 256, 0, stream>>>(x, emb, out);
  finalize_a<<<1, 1024, 0, stream>>>(ema_size, ws, out);
  finalize_b<<<Ec * Dc / 256, 256, 0, stream>>>(ema_w, ws, out);
}